// Round 2
// baseline (427.844 us; speedup 1.0000x reference)
//
#include <hip/hip_runtime.h>
#include <hip/hip_bf16.h>

// BaseQVLayer, R15:
//   xb/yb = bf16(x/y)             (k_cvt)
//   xp = x@Wx+bx; yp = y@Wy+by    (k_proj + row-norms, old gemm_core)
//   zT = Wg^T @ xp^T [512 x 8192] (k_zT, old gemm_core)
//   At[j,i] = 2*(yp_j.xp_i)/(Dx_i+Dy_j)   (k_aff, deep core, B-from-L2)
//   p0/p1 = At @ z split-K halves (k_agg, deep core, B-from-L2)
//   out = relu(p0+p1+bg)                  (k_fin)
//
// R15 delta: R14 post-mortem showed k_agg/k_aff are LDS-THROUGHPUT-bound
// (k_agg: 96 KB LDS/CU-window ~1130cyc vs 614cyc MFMA; MfmaUtil 29.7%,
// VALUBusy 15%, HBM 15% -- nothing else near ceiling). Fix: B operand no
// longer staged in LDS. B is L2/L3-hot (zT 8 MB L3-resident; xpb ~1 MB
// rolling set/XCD). B fragments load DIRECTLY global->VGPR (lane pattern
// row=bn+wn+j*16+l15, k=k0+quad*8 -> 16 rows x 64B fully-used lines),
// DOUBLE-BUFFERED in registers one iter ahead, issued right after the
// barrier BEFORE the A cp16s so the compiler's B-wait never drains the A
// prefetch queue. Counted vmcnt = (RING-2)*(CPA+FB). LDS traffic halves:
// k_agg 48 KB/CU-window ~565cyc < 614 MFMA; k_aff 96 KB ~1130 < 1229.
// Both flip to MFMA-gated. Ring/barrier/race structure unchanged from R14.
//
// Workspace 154.6 MB (unchanged): At [0,128 MB) with xb@0 / yb@16MB
// aliased; xpb 8 | ypb 8 | zT 8 | WxT 1 | WyT 1 | WgT .5 | Dx,Dy.
// p0/p1 alias xpb/ypb (dead after k_aff).

typedef __attribute__((ext_vector_type(8))) short bf16x8;
typedef __attribute__((ext_vector_type(4))) short bf16x4;
typedef __attribute__((ext_vector_type(4))) float f32x4;

__device__ __forceinline__ short f2b(float f) {
    unsigned int u = __builtin_bit_cast(unsigned int, f);
    unsigned int r = (u + 0x7fffu + ((u >> 16) & 1u)) >> 16;
    return (short)r;
}
__device__ __forceinline__ float b2f(short s) {
    unsigned int u = ((unsigned int)(unsigned short)s) << 16;
    return __builtin_bit_cast(float, u);
}

// async global->LDS, 16 B/lane. LDS dest = wave-uniform base + lane*16.
__device__ __forceinline__ void cp16(const void* g, void* l) {
    __builtin_amdgcn_global_load_lds(
        (const __attribute__((address_space(1))) void*)g,
        (__attribute__((address_space(3))) void*)l, 16, 0, 0);
}

template<int N>
__device__ __forceinline__ void waitvm() {
    if constexpr (N == 0)       asm volatile("s_waitcnt vmcnt(0)" ::: "memory");
    else if constexpr (N == 2)  asm volatile("s_waitcnt vmcnt(2)" ::: "memory");
    else if constexpr (N == 4)  asm volatile("s_waitcnt vmcnt(4)" ::: "memory");
    else if constexpr (N == 6)  asm volatile("s_waitcnt vmcnt(6)" ::: "memory");
    else if constexpr (N == 8)  asm volatile("s_waitcnt vmcnt(8)" ::: "memory");
    else if constexpr (N == 10) asm volatile("s_waitcnt vmcnt(10)" ::: "memory");
    else if constexpr (N == 12) asm volatile("s_waitcnt vmcnt(12)" ::: "memory");
    else if constexpr (N == 16) asm volatile("s_waitcnt vmcnt(16)" ::: "memory");
    else static_assert(N == 0, "unsupported vmcnt literal");
}

constexpr int EPI_XP = 0;  // +bias, store bf16, atomic row-norm
constexpr int EPI_BF = 1;  // store bf16 (zT, k_agg partials)
constexpr int EPI_AT = 2;  // dice scale (rcp), store bf16

// ===================== old 2-barrier core (k_proj / k_zT only) =============
template<int EPI, int TM, int TN, int WVN>
__device__ __forceinline__ void gemm_core(
    const short* __restrict__ A, int lda,
    const short* __restrict__ Bt, int ldb,
    int N, int K, int bm, int bn, int kbase,
    const float* __restrict__ bias,
    short* __restrict__ outb,
    float* __restrict__ Dacc)
{
    constexpr int WN  = WVN;
    constexpr int WM  = 4 / WN;
    constexpr int FRN = TN / WN / 16;
    constexpr int FRM = TM / WM / 16;
    __shared__ __align__(16) short As[TM * 32];
    __shared__ __align__(16) short Bs[TN * 32];

    const int tid  = threadIdx.x;
    const int wave = tid >> 6;
    const int lane = tid & 63;
    const int quad = lane >> 4;
    const int l15  = lane & 15;
    const int wn   = (wave % WN) * (FRN * 16);
    const int wm   = (wave / WN) * (FRM * 16);

    f32x4 acc[FRM][FRN];
#pragma unroll
    for (int i = 0; i < FRM; i++)
#pragma unroll
        for (int j = 0; j < FRN; j++) acc[i][j] = f32x4{0.f, 0.f, 0.f, 0.f};

    for (int k0 = kbase; k0 < kbase + K; k0 += 32) {
#pragma unroll
        for (int s = 0; s < TM / 64; s++) {
            const int seg = tid + 256 * s;
            const int row = seg >> 2, c8 = seg & 3;
            const int gg  = c8 ^ (row & 3);
            cp16(&A[(size_t)(bm + row) * lda + k0 + gg * 8], &As[seg * 8]);
        }
#pragma unroll
        for (int s = 0; s < TN / 64; s++) {
            const int seg = tid + 256 * s;
            const int row = seg >> 2, c8 = seg & 3;
            const int gg  = c8 ^ (row & 3);
            cp16(&Bt[(size_t)(bn + row) * ldb + k0 + gg * 8], &Bs[seg * 8]);
        }
        __syncthreads();

        bf16x8 a[FRM], b[FRN];
#pragma unroll
        for (int i = 0; i < FRM; i++) {
            const int row = wm + i * 16 + l15;
            a[i] = *(const bf16x8*)&As[row * 32 + ((quad ^ (row & 3)) << 3)];
        }
#pragma unroll
        for (int j = 0; j < FRN; j++) {
            const int row = wn + j * 16 + l15;
            b[j] = *(const bf16x8*)&Bs[row * 32 + ((quad ^ (row & 3)) << 3)];
        }
#pragma unroll
        for (int i = 0; i < FRM; i++)
#pragma unroll
            for (int j = 0; j < FRN; j++)
                acc[i][j] = __builtin_amdgcn_mfma_f32_16x16x32_bf16(a[i], b[j], acc[i][j], 0, 0, 0);
        __syncthreads();
    }

    // C/D layout: col = lane&15, row = quad*4 + r  [m89/m91]
#pragma unroll
    for (int im = 0; im < FRM; ++im) {
#pragma unroll
        for (int r = 0; r < 4; ++r) {
            const int gm = bm + wm + im * 16 + quad * 4 + r;
            if (EPI == EPI_XP) {
                float s = 0.f;
#pragma unroll
                for (int jn = 0; jn < FRN; ++jn) {
                    const int gn = bn + wn + jn * 16 + l15;
                    const float v = acc[im][jn][r] + bias[gn];
                    outb[(size_t)gm * N + gn] = f2b(v);
                    s += v * v;
                }
#pragma unroll
                for (int m = 1; m < 16; m <<= 1) s += __shfl_xor(s, m, 64);
                if (l15 == 0) atomicAdd(&Dacc[gm], s);
            } else {  // EPI_BF
#pragma unroll
                for (int jn = 0; jn < FRN; ++jn) {
                    const int gn = bn + wn + jn * 16 + l15;
                    outb[(size_t)gm * N + gn] = f2b(acc[im][jn][r]);
                }
            }
        }
    }
}

// ===================== deep-pipelined core (k_aff / k_agg) =================
// 256 threads, waves 2x2: wave tile (TM/2) x (TN/2). BK=32. A in RING LDS
// slots (cp16, counted vmcnt, raw s_barrier). B fragments DIRECT from
// global (L2/L3-hot), double-buffered in registers one iteration ahead.
// Issue order per iter: [waitA][barrier][loadB(t+1)][stageA(t+RING-1)]
// [ds_read A][MFMA w/ B(t)][lgkmcnt(0)][bc<-bnx]. loadB precedes stageA so
// the compiler's wait-for-B counts only (FB+CPA) newer ops and never
// drains the deeper A prefetch queue.
template<int EPI, int TM, int TN, int RING>
__device__ __forceinline__ void gemm_deep(
    const short* __restrict__ A, int lda,
    const short* __restrict__ Bt, int ldb,
    int N, int K, int bm, int bn, int kbase,
    short* __restrict__ outb,
    const float* __restrict__ Drow, const float* __restrict__ Dcol)
{
    constexpr int FRM = TM / 32;           // frags per wave along m
    constexpr int FRN = TN / 32;           // frags per wave along n
    constexpr int CPA = TM * 4 / 256;      // cp16/thread for A tile
    constexpr int FB  = FRN;               // B global loads/thread/iter
    __shared__ __align__(16) short As[RING][TM * 32];

    const int tid  = threadIdx.x;
    const int wave = tid >> 6;
    const int lane = tid & 63;
    const int quad = lane >> 4;
    const int l15  = lane & 15;
    const int wm   = (wave >> 1) * (FRM * 16);
    const int wn   = (wave & 1) * (FRN * 16);
    const int nk   = K / 32;

    // per-lane B row pointers (16B-aligned: ldb even, kbase mult 32)
    const short* bp[FRN];
#pragma unroll
    for (int j = 0; j < FRN; j++)
        bp[j] = Bt + (size_t)(bn + wn + j * 16 + l15) * ldb + kbase + quad * 8;

    f32x4 acc[FRM][FRN];
#pragma unroll
    for (int i = 0; i < FRM; i++)
#pragma unroll
        for (int j = 0; j < FRN; j++) acc[i][j] = f32x4{0.f, 0.f, 0.f, 0.f};

    auto stageA = [&](int slot, int t) {
        const int k0 = kbase + t * 32;
#pragma unroll
        for (int s = 0; s < CPA; s++) {
            const int seg = tid + 256 * s;
            const int row = seg >> 2, c8 = seg & 3;
            const int gg  = c8 ^ (row & 3);
            cp16(&A[(size_t)(bm + row) * lda + k0 + gg * 8], &As[slot][seg * 8]);
        }
    };

#pragma unroll
    for (int p = 0; p < RING - 1; ++p) stageA(p, p);   // A prefill
    bf16x8 bc[FRN], bnx[FRN];
#pragma unroll
    for (int j = 0; j < FRN; j++) bc[j] = *(const bf16x8*)(bp[j]);  // B(0)

    int cur = 0, prv = RING - 1;
    for (int t = 0; t < nk; ++t) {
        // A tile t landed when <= (iters since its issue)*(CPA+FB) newer
        // vmem ops remain. Tail ladder conservative (over-waits only).
        if constexpr (RING == 3) {
            if (t + 1 < nk) waitvm<CPA + FB>();
            else            waitvm<0>();
        } else {
            if (t + 2 < nk)      waitvm<2 * (CPA + FB)>();
            else if (t + 1 < nk) waitvm<CPA + FB>();
            else                 waitvm<0>();
        }
        __builtin_amdgcn_s_barrier();
        if (t + 1 < nk) {
#pragma unroll
            for (int j = 0; j < FRN; j++)
                bnx[j] = *(const bf16x8*)(bp[j] + (size_t)(t + 1) * 32);
        }
        // slot prv == (t-1)%RING: last read at iter t-1, synced by barrier
        if (t + RING - 1 < nk) stageA(prv, t + RING - 1);

        bf16x8 a[FRM];
#pragma unroll
        for (int i = 0; i < FRM; i++) {
            const int row = wm + i * 16 + l15;
            a[i] = *(const bf16x8*)&As[cur][row * 32 + ((quad ^ (row & 3)) << 3)];
        }
        __builtin_amdgcn_s_setprio(1);
#pragma unroll
        for (int i = 0; i < FRM; i++)
#pragma unroll
            for (int j = 0; j < FRN; j++)
                acc[i][j] = __builtin_amdgcn_mfma_f32_16x16x32_bf16(a[i], bc[j], acc[i][j], 0, 0, 0);
        __builtin_amdgcn_s_setprio(0);
        // pin in-flight ds_reads before the next barrier can admit a cp16
        // refill of this slot (in-flight-read vs LDS-write race)
        asm volatile("s_waitcnt lgkmcnt(0)" ::: "memory");
        if (t + 1 < nk) {
#pragma unroll
            for (int j = 0; j < FRN; j++) bc[j] = bnx[j];
        }
        prv = cur;
        cur = (cur + 1 == RING) ? 0 : cur + 1;
    }

    // C/D layout: col = lane&15, row = quad*4 + r  [m89/m91]
    if (EPI == EPI_AT) {
        float dcol[FRN];
#pragma unroll
        for (int jn = 0; jn < FRN; ++jn) dcol[jn] = Dcol[bn + wn + jn * 16 + l15];
#pragma unroll
        for (int im = 0; im < FRM; ++im) {
#pragma unroll
            for (int r = 0; r < 4; ++r) {
                const int gm = bm + wm + im * 16 + quad * 4 + r;
                const float dy = Drow[gm];
#pragma unroll
                for (int jn = 0; jn < FRN; ++jn) {
                    const int gn = bn + wn + jn * 16 + l15;
                    const float v = 2.f * acc[im][jn][r] * __builtin_amdgcn_rcpf(dcol[jn] + dy);
                    outb[(size_t)gm * N + gn] = f2b(v);
                }
            }
        }
    } else {  // EPI_BF
#pragma unroll
        for (int im = 0; im < FRM; ++im) {
#pragma unroll
            for (int r = 0; r < 4; ++r) {
                const int gm = bm + wm + im * 16 + quad * 4 + r;
#pragma unroll
                for (int jn = 0; jn < FRN; ++jn) {
                    const int gn = bn + wn + jn * 16 + l15;
                    outb[(size_t)gm * N + gn] = f2b(acc[im][jn][r]);
                }
            }
        }
    }
}

// xp/yp = x@W + b (bf16 A via cp16), row norms. grid(4,128), tile 64x128.
__global__ __launch_bounds__(256)
void k_proj(const short* __restrict__ A, const short* __restrict__ Bt,
            const float* __restrict__ bias, short* __restrict__ outb,
            float* __restrict__ Dacc)
{
    gemm_core<EPI_XP, 64, 128, 2>(A, 1024, Bt, 1024, 512, 1024,
                                  blockIdx.y * 64, blockIdx.x * 128, 0,
                                  bias, outb, Dacc);
}

// zT = Wg^T @ xp^T  [512 x 8192] bf16. grid(64,8), tile 64x128, K=512.
__global__ __launch_bounds__(256)
void k_zT(const short* __restrict__ WgT, const short* __restrict__ xpb,
          short* __restrict__ zT)
{
    gemm_core<EPI_BF, 64, 128, 2>(WgT, 512, xpb, 512, 8192, 512,
                                  blockIdx.y * 64, blockIdx.x * 128, 0,
                                  nullptr, zT, nullptr);
}

// At[j,i]. flat grid 2048; deep core, tile 256x128 (wave 128x64), RING=3
// (48 KB LDS, 2 blk/CU). XCD x owns j-band; ~8 consecutive bx share an xp
// slice in L2; B (xpb) loads direct from L2/L3.
__global__ __launch_bounds__(256, 2)
void k_aff(const short* __restrict__ ypb, const short* __restrict__ xpb,
           short* __restrict__ At, const float* __restrict__ Dy,
           const float* __restrict__ Dx)
{
    const int flat = blockIdx.x;
    const int xcd = flat & 7;
    const int q   = flat >> 3;            // 0..255
    const int by  = xcd * 4 + (q & 3);    // 0..31  (j tiles of 256)
    const int bx  = q >> 2;               // 0..63  (i tiles of 128)
    gemm_deep<EPI_AT, 256, 128, 3>(ypb, 512, xpb, 512, 8192, 512,
                                   by * 256, bx * 128, 0, At, Dy, Dx);
}

// Split-K At@z partials. deep core, tile 128x128, RING=4 (depth-2 A
// prefetch covers HBM At latency), 32 KB LDS, grid 512 (2 blk/CU).
// Group = (bm,z): its 4 bn-blocks on one XCD so the 1 MB At slice is
// L2-shared; B (zT) loads direct from L2/L3 (8 MB, L3-resident).
__global__ __launch_bounds__(256, 2)
void k_agg(const short* __restrict__ At, const short* __restrict__ zT,
           short* __restrict__ p0, short* __restrict__ p1)
{
    const int flat = blockIdx.x;
    const int xcd = flat & 7;
    const int q   = flat >> 3;            // 0..63 within XCD
    const int g   = xcd * 16 + (q >> 2);  // group 0..127 = (bm, z)
    const int bm  = (g >> 1) * 128;
    const int z   = g & 1;
    const int bn  = (q & 3) * 128;
    short* outb = z ? p1 : p0;
    gemm_deep<EPI_BF, 128, 128, 4>(At, 8192, zT, 8192, 512, 4096,
                                   bm, bn, z * 4096, outb, nullptr, nullptr);
}

// out = relu(p0 + p1 + bg). 8 elems/thread, 2048 blocks.
__global__ __launch_bounds__(256)
void k_fin(const short* __restrict__ p0, const short* __restrict__ p1,
           const float* __restrict__ bg, float* __restrict__ out)
{
    const int idx = (blockIdx.x * 256 + threadIdx.x) * 8;
    const int col = idx & 511;
    const bf16x8 a = *(const bf16x8*)&p0[idx];
    const bf16x8 b = *(const bf16x8*)&p1[idx];
    const f32x4 g0 = *(const f32x4*)&bg[col];
    const f32x4 g1 = *(const f32x4*)&bg[col + 4];
    f32x4 o0, o1;
#pragma unroll
    for (int e = 0; e < 4; ++e) {
        o0[e] = fmaxf(b2f(a[e]) + b2f(b[e]) + g0[e], 0.f);
        o1[e] = fmaxf(b2f(a[e + 4]) + b2f(b[e + 4]) + g1[e], 0.f);
    }
    *(f32x4*)&out[idx]     = o0;
    *(f32x4*)&out[idx + 4] = o1;
}

// =========================== helpers =======================================
__global__ __launch_bounds__(256)
void k_cvt(const float* __restrict__ in, short* __restrict__ out)
{
    const int i = (blockIdx.x * 256 + threadIdx.x) * 4;
    const float4 v = *(const float4*)&in[i];
    bf16x4 b;
    b[0] = f2b(v.x); b[1] = f2b(v.y); b[2] = f2b(v.z); b[3] = f2b(v.w);
    *(bf16x4*)&out[i] = b;
}

__global__ __launch_bounds__(256)
void transpose_f32_bf16(const float* __restrict__ in, short* __restrict__ out, int R, int C)
{
    __shared__ short t[32][33];
    const int tx = threadIdx.x, ty = threadIdx.y;
    const int bx = blockIdx.x * 32, by = blockIdx.y * 32;
#pragma unroll
    for (int i = 0; i < 32; i += 8)
        t[ty + i][tx] = f2b(in[(size_t)(by + ty + i) * C + bx + tx]);
    __syncthreads();
#pragma unroll
    for (int i = 0; i < 32; i += 8)
        out[(size_t)(bx + ty + i) * R + by + tx] = t[tx][ty + i];
}

extern "C" void kernel_launch(void* const* d_in, const int* in_sizes, int n_in,
                              void* d_out, int out_size, void* d_ws, size_t ws_size,
                              hipStream_t stream)
{
    const float* x  = (const float*)d_in[0];
    const float* y  = (const float*)d_in[1];
    const float* Wx = (const float*)d_in[2];
    const float* bx = (const float*)d_in[3];
    const float* Wy = (const float*)d_in[4];
    const float* by = (const float*)d_in[5];
    const float* Wg = (const float*)d_in[6];
    const float* bg = (const float*)d_in[7];
    float* out = (float*)d_out;                // [8192, 512] f32

    char* p = (char*)d_ws;
    short* At   = (short*)p;                   // [0, 128 MB)
    short* xb   = (short*)p;                   // 16 MB, aliases At (dead by k_aff)
    short* yb   = (short*)(p + (size_t)8192 * 1024 * 2);   // next 16 MB, ditto
    p += (size_t)8192 * 8192 * 2;
    short* xpb  = (short*)p; p += (size_t)8192 * 512 * 2;
    short* ypb  = (short*)p; p += (size_t)8192 * 512 * 2;
    short* zT   = (short*)p; p += (size_t)512 * 8192 * 2;
    short* WxT  = (short*)p; p += (size_t)512 * 1024 * 2;
    short* WyT  = (short*)p; p += (size_t)512 * 1024 * 2;
    short* WgT  = (short*)p; p += (size_t)512 * 512 * 2;
    float* Dx   = (float*)p; p += (size_t)8192 * 4;
    float* Dy   = (float*)p; p += (size_t)8192 * 4;
    // split-K partials alias xpb/ypb (dead after k_aff)
    short* p0 = xpb;
    short* p1 = ypb;

    hipMemsetAsync(Dx, 0, 2 * 8192 * sizeof(float), stream);  // Dx,Dy contiguous

    dim3 tb(32, 8);
    transpose_f32_bf16<<<dim3(512 / 32, 1024 / 32), tb, 0, stream>>>(Wx, WxT, 1024, 512);
    transpose_f32_bf16<<<dim3(512 / 32, 1024 / 32), tb, 0, stream>>>(Wy, WyT, 1024, 512);
    transpose_f32_bf16<<<dim3(512 / 32, 512 / 32),  tb, 0, stream>>>(Wg, WgT, 512, 512);

    k_cvt<<<8192, 256, 0, stream>>>(x, xb);
    k_cvt<<<8192, 256, 0, stream>>>(y, yb);

    k_proj<<<dim3(4, 128), 256, 0, stream>>>(xb, WxT, bx, xpb, Dx);
    k_proj<<<dim3(4, 128), 256, 0, stream>>>(yb, WyT, by, ypb, Dy);

    k_zT<<<dim3(64, 8), 256, 0, stream>>>(WgT, xpb, zT);

    k_aff<<<2048, 256, 0, stream>>>(ypb, xpb, At, Dy, Dx);

    k_agg<<<512, 256, 0, stream>>>(At, zT, p0, p1);

    k_fin<<<2048, 256, 0, stream>>>(p0, p1, bg, out);
}

// Round 4
// 353.278 us; speedup vs baseline: 1.2111x; 1.2111x over previous
//
#include <hip/hip_runtime.h>
#include <hip/hip_bf16.h>

// BaseQVLayer, R16 (resubmit — R3 bench was an infra failure, no signal):
//   xb/yb = bf16(x/y)             (k_cvt)
//   xp = x@Wx+bx; yp = y@Wy+by    (k_proj + row-norms, old gemm_core)
//   zT = Wg^T @ xp^T [512 x 8192] (k_zT, old gemm_core)
//   At[j,i] = 2*(yp_j.xp_i)/(Dx_i+Dy_j)   (k_aff, deep core)
//   p0/p1 = At @ z split-K halves (k_agg, deep core)
//   out = relu(p0+p1+bg)                  (k_fin)
//
// R16 delta: (a) REVERT R15's direct-global B (148us regression: exposed
// L2 latency at the bc<-bnx copy, ~300cyc MFMA cover insufficient; LDS
// read BW is 256B/cyc [rocminfo], not the binding term). Back to R14's
// proven both-operands-in-LDS RING pipeline (k_agg 98us).
// (b) FIX the granule swizzle. Old: slot = quad^(row&3). Bank-group =
// (4*row + slot) mod 8 has period 4 over rows but 8-lane read passes span
// 8 rows -> rows r,r+4 collide -> every pass 2-way conflicted
// (SQ_LDS_BANK_CONFLICT 8.4M/dispatch ~= base read time; R12's
// "structural minimum" claim contradicted by m201's 267K). New:
// slot = quad ^ (row&3) ^ ((row>>2)&3): rows 0..7 map to BGs
// {0,5,2,7,1,4,3,6} -- all distinct, conflict-free. Applied on BOTH the
// cp16 SOURCE address and the ds_read slot (same involution, LDS dest
// linear, rule #21) => bit-identical numerics, zero layout risk.
//
// Workspace 154.6 MB (unchanged): At [0,128 MB) with xb@0 / yb@16MB
// aliased; xpb 8 | ypb 8 | zT 8 | WxT 1 | WyT 1 | WgT .5 | Dx,Dy.
// p0/p1 alias xpb/ypb (dead after k_aff).

typedef __attribute__((ext_vector_type(8))) short bf16x8;
typedef __attribute__((ext_vector_type(4))) short bf16x4;
typedef __attribute__((ext_vector_type(4))) float f32x4;

__device__ __forceinline__ short f2b(float f) {
    unsigned int u = __builtin_bit_cast(unsigned int, f);
    unsigned int r = (u + 0x7fffu + ((u >> 16) & 1u)) >> 16;
    return (short)r;
}
__device__ __forceinline__ float b2f(short s) {
    unsigned int u = ((unsigned int)(unsigned short)s) << 16;
    return __builtin_bit_cast(float, u);
}

// async global->LDS, 16 B/lane. LDS dest = wave-uniform base + lane*16.
__device__ __forceinline__ void cp16(const void* g, void* l) {
    __builtin_amdgcn_global_load_lds(
        (const __attribute__((address_space(1))) void*)g,
        (__attribute__((address_space(3))) void*)l, 16, 0, 0);
}

template<int N>
__device__ __forceinline__ void waitvm() {
    if constexpr (N == 0)      asm volatile("s_waitcnt vmcnt(0)" ::: "memory");
    else if constexpr (N == 4) asm volatile("s_waitcnt vmcnt(4)" ::: "memory");
    else if constexpr (N == 6) asm volatile("s_waitcnt vmcnt(6)" ::: "memory");
    else if constexpr (N == 8) asm volatile("s_waitcnt vmcnt(8)" ::: "memory");
    else static_assert(N == 0, "unsupported vmcnt literal");
}

// conflict-free granule slot: bank-group (4*row + slot) mod 8 distinct
// over any 8 consecutive rows (see R16 header).
__device__ __forceinline__ int gslot(int c, int row) {
    return c ^ (row & 3) ^ ((row >> 2) & 3);
}

constexpr int EPI_XP = 0;  // +bias, store bf16, atomic row-norm
constexpr int EPI_BF = 1;  // store bf16 (zT, k_agg partials)
constexpr int EPI_AT = 2;  // dice scale (rcp), store bf16

// ===================== old 2-barrier core (k_proj / k_zT only) =============
template<int EPI, int TM, int TN, int WVN>
__device__ __forceinline__ void gemm_core(
    const short* __restrict__ A, int lda,
    const short* __restrict__ Bt, int ldb,
    int N, int K, int bm, int bn, int kbase,
    const float* __restrict__ bias,
    short* __restrict__ outb,
    float* __restrict__ Dacc)
{
    constexpr int WN  = WVN;
    constexpr int WM  = 4 / WN;
    constexpr int FRN = TN / WN / 16;
    constexpr int FRM = TM / WM / 16;
    __shared__ __align__(16) short As[TM * 32];
    __shared__ __align__(16) short Bs[TN * 32];

    const int tid  = threadIdx.x;
    const int wave = tid >> 6;
    const int lane = tid & 63;
    const int quad = lane >> 4;
    const int l15  = lane & 15;
    const int wn   = (wave % WN) * (FRN * 16);
    const int wm   = (wave / WN) * (FRM * 16);

    f32x4 acc[FRM][FRN];
#pragma unroll
    for (int i = 0; i < FRM; i++)
#pragma unroll
        for (int j = 0; j < FRN; j++) acc[i][j] = f32x4{0.f, 0.f, 0.f, 0.f};

    for (int k0 = kbase; k0 < kbase + K; k0 += 32) {
#pragma unroll
        for (int s = 0; s < TM / 64; s++) {
            const int seg = tid + 256 * s;
            const int row = seg >> 2, c8 = seg & 3;
            const int gg  = gslot(c8, row);
            cp16(&A[(size_t)(bm + row) * lda + k0 + gg * 8], &As[seg * 8]);
        }
#pragma unroll
        for (int s = 0; s < TN / 64; s++) {
            const int seg = tid + 256 * s;
            const int row = seg >> 2, c8 = seg & 3;
            const int gg  = gslot(c8, row);
            cp16(&Bt[(size_t)(bn + row) * ldb + k0 + gg * 8], &Bs[seg * 8]);
        }
        __syncthreads();

        bf16x8 a[FRM], b[FRN];
#pragma unroll
        for (int i = 0; i < FRM; i++) {
            const int row = wm + i * 16 + l15;
            a[i] = *(const bf16x8*)&As[row * 32 + (gslot(quad, row) << 3)];
        }
#pragma unroll
        for (int j = 0; j < FRN; j++) {
            const int row = wn + j * 16 + l15;
            b[j] = *(const bf16x8*)&Bs[row * 32 + (gslot(quad, row) << 3)];
        }
#pragma unroll
        for (int i = 0; i < FRM; i++)
#pragma unroll
            for (int j = 0; j < FRN; j++)
                acc[i][j] = __builtin_amdgcn_mfma_f32_16x16x32_bf16(a[i], b[j], acc[i][j], 0, 0, 0);
        __syncthreads();
    }

    // C/D layout: col = lane&15, row = quad*4 + r  [m89/m91]
#pragma unroll
    for (int im = 0; im < FRM; ++im) {
#pragma unroll
        for (int r = 0; r < 4; ++r) {
            const int gm = bm + wm + im * 16 + quad * 4 + r;
            if (EPI == EPI_XP) {
                float s = 0.f;
#pragma unroll
                for (int jn = 0; jn < FRN; ++jn) {
                    const int gn = bn + wn + jn * 16 + l15;
                    const float v = acc[im][jn][r] + bias[gn];
                    outb[(size_t)gm * N + gn] = f2b(v);
                    s += v * v;
                }
#pragma unroll
                for (int m = 1; m < 16; m <<= 1) s += __shfl_xor(s, m, 64);
                if (l15 == 0) atomicAdd(&Dacc[gm], s);
            } else {  // EPI_BF
#pragma unroll
                for (int jn = 0; jn < FRN; ++jn) {
                    const int gn = bn + wn + jn * 16 + l15;
                    outb[(size_t)gm * N + gn] = f2b(acc[im][jn][r]);
                }
            }
        }
    }
}

// ===================== deep-pipelined core (k_aff / k_agg) =================
// 256 threads, waves 2x2: wave tile (TM/2) x (TN/2). BK=32, RING LDS slots,
// raw s_barrier + counted vmcnt, stage issued RING-1 tiles ahead. Both
// operands LDS-staged (R14 structure, proven).
template<int EPI, int TM, int TN, int RING>
__device__ __forceinline__ void gemm_deep(
    const short* __restrict__ A, int lda,
    const short* __restrict__ Bt, int ldb,
    int N, int K, int bm, int bn, int kbase,
    short* __restrict__ outb,
    const float* __restrict__ Drow, const float* __restrict__ Dcol)
{
    constexpr int FRM = TM / 32;           // frags per wave along m
    constexpr int FRN = TN / 32;           // frags per wave along n
    constexpr int CPA = TM * 4 / 256;      // cp16/thread for A tile
    constexpr int CPB = TN * 4 / 256;      // cp16/thread for B tile
    constexpr int CPT = CPA + CPB;
    __shared__ __align__(16) short As[RING][TM * 32];
    __shared__ __align__(16) short Bs[RING][TN * 32];

    const int tid  = threadIdx.x;
    const int wave = tid >> 6;
    const int lane = tid & 63;
    const int quad = lane >> 4;
    const int l15  = lane & 15;
    const int wm   = (wave >> 1) * (FRM * 16);
    const int wn   = (wave & 1) * (FRN * 16);
    const int nk   = K / 32;

    f32x4 acc[FRM][FRN];
#pragma unroll
    for (int i = 0; i < FRM; i++)
#pragma unroll
        for (int j = 0; j < FRN; j++) acc[i][j] = f32x4{0.f, 0.f, 0.f, 0.f};

    auto stage = [&](int slot, int t) {
        const int k0 = kbase + t * 32;
#pragma unroll
        for (int s = 0; s < CPA; s++) {
            const int seg = tid + 256 * s;
            const int row = seg >> 2, c8 = seg & 3;
            const int gg  = gslot(c8, row);
            cp16(&A[(size_t)(bm + row) * lda + k0 + gg * 8], &As[slot][seg * 8]);
        }
#pragma unroll
        for (int s = 0; s < CPB; s++) {
            const int seg = tid + 256 * s;
            const int row = seg >> 2, c8 = seg & 3;
            const int gg  = gslot(c8, row);
            cp16(&Bt[(size_t)(bn + row) * ldb + k0 + gg * 8], &Bs[slot][seg * 8]);
        }
    };

#pragma unroll
    for (int p = 0; p < RING - 1; ++p) stage(p, p);   // prefill

    int cur = 0, prv = RING - 1;
    for (int t = 0; t < nk; ++t) {
        // tile t landed when <= CPT*(tiles in flight beyond t) outstanding
        if constexpr (RING == 3) {
            if (t + 1 < nk) waitvm<CPT>(); else waitvm<0>();
        } else {
            if (t + 2 < nk)      waitvm<2 * CPT>();
            else if (t + 1 < nk) waitvm<CPT>();
            else                 waitvm<0>();
        }
        __builtin_amdgcn_s_barrier();
        // slot prv == (t-1)%RING: last read at iter t-1, synced by barrier above
        if (t + RING - 1 < nk) stage(prv, t + RING - 1);

        bf16x8 a[FRM], b[FRN];
#pragma unroll
        for (int i = 0; i < FRM; i++) {
            const int row = wm + i * 16 + l15;
            a[i] = *(const bf16x8*)&As[cur][row * 32 + (gslot(quad, row) << 3)];
        }
#pragma unroll
        for (int j = 0; j < FRN; j++) {
            const int row = wn + j * 16 + l15;
            b[j] = *(const bf16x8*)&Bs[cur][row * 32 + (gslot(quad, row) << 3)];
        }
        __builtin_amdgcn_s_setprio(1);
#pragma unroll
        for (int i = 0; i < FRM; i++)
#pragma unroll
            for (int j = 0; j < FRN; j++)
                acc[i][j] = __builtin_amdgcn_mfma_f32_16x16x32_bf16(a[i], b[j], acc[i][j], 0, 0, 0);
        __builtin_amdgcn_s_setprio(0);
        // pin in-flight ds_reads before the next barrier can admit a cp16
        // refill of this slot (in-flight-read vs LDS-write race)
        asm volatile("s_waitcnt lgkmcnt(0)" ::: "memory");
        prv = cur;
        cur = (cur + 1 == RING) ? 0 : cur + 1;
    }

    // C/D layout: col = lane&15, row = quad*4 + r  [m89/m91]
    if (EPI == EPI_AT) {
        float dcol[FRN];
#pragma unroll
        for (int jn = 0; jn < FRN; ++jn) dcol[jn] = Dcol[bn + wn + jn * 16 + l15];
#pragma unroll
        for (int im = 0; im < FRM; ++im) {
#pragma unroll
            for (int r = 0; r < 4; ++r) {
                const int gm = bm + wm + im * 16 + quad * 4 + r;
                const float dy = Drow[gm];
#pragma unroll
                for (int jn = 0; jn < FRN; ++jn) {
                    const int gn = bn + wn + jn * 16 + l15;
                    const float v = 2.f * acc[im][jn][r] * __builtin_amdgcn_rcpf(dcol[jn] + dy);
                    outb[(size_t)gm * N + gn] = f2b(v);
                }
            }
        }
    } else {  // EPI_BF
#pragma unroll
        for (int im = 0; im < FRM; ++im) {
#pragma unroll
            for (int r = 0; r < 4; ++r) {
                const int gm = bm + wm + im * 16 + quad * 4 + r;
#pragma unroll
                for (int jn = 0; jn < FRN; ++jn) {
                    const int gn = bn + wn + jn * 16 + l15;
                    outb[(size_t)gm * N + gn] = f2b(acc[im][jn][r]);
                }
            }
        }
    }
}

// xp/yp = x@W + b (bf16 A via cp16), row norms. grid(4,128), tile 64x128.
__global__ __launch_bounds__(256)
void k_proj(const short* __restrict__ A, const short* __restrict__ Bt,
            const float* __restrict__ bias, short* __restrict__ outb,
            float* __restrict__ Dacc)
{
    gemm_core<EPI_XP, 64, 128, 2>(A, 1024, Bt, 1024, 512, 1024,
                                  blockIdx.y * 64, blockIdx.x * 128, 0,
                                  bias, outb, Dacc);
}

// zT = Wg^T @ xp^T  [512 x 8192] bf16. grid(64,8), tile 64x128, K=512.
__global__ __launch_bounds__(256)
void k_zT(const short* __restrict__ WgT, const short* __restrict__ xpb,
          short* __restrict__ zT)
{
    gemm_core<EPI_BF, 64, 128, 2>(WgT, 512, xpb, 512, 8192, 512,
                                  blockIdx.y * 64, blockIdx.x * 128, 0,
                                  nullptr, zT, nullptr);
}

// At[j,i]. flat grid 2048; deep core, tile 256x128 (wave 128x64), RING=3
// (72 KB LDS, 2 blk/CU). XCD x owns j-band; 4 consecutive blocks share an
// xp 128-row tile (L2).
__global__ __launch_bounds__(256, 2)
void k_aff(const short* __restrict__ ypb, const short* __restrict__ xpb,
           short* __restrict__ At, const float* __restrict__ Dy,
           const float* __restrict__ Dx)
{
    const int flat = blockIdx.x;
    const int xcd = flat & 7;
    const int q   = flat >> 3;            // 0..255
    const int by  = xcd * 4 + (q & 3);    // 0..31  (j tiles of 256)
    const int bx  = q >> 2;               // 0..63  (i tiles of 128)
    gemm_deep<EPI_AT, 256, 128, 3>(ypb, 512, xpb, 512, 8192, 512,
                                   by * 256, bx * 128, 0, At, Dy, Dx);
}

// Split-K At@z partials. deep core, tile 128x128, RING=4 (depth-2 A
// prefetch covers HBM At latency), 64 KB LDS, grid 512 (2 blk/CU).
// Group = (bm,z): its 4 bn-blocks on one XCD so the 1 MB At slice is
// L2-shared; z-halves read disjoint At columns.
__global__ __launch_bounds__(256, 2)
void k_agg(const short* __restrict__ At, const short* __restrict__ zT,
           short* __restrict__ p0, short* __restrict__ p1)
{
    const int flat = blockIdx.x;
    const int xcd = flat & 7;
    const int q   = flat >> 3;            // 0..63 within XCD
    const int g   = xcd * 16 + (q >> 2);  // group 0..127 = (bm, z)
    const int bm  = (g >> 1) * 128;
    const int z   = g & 1;
    const int bn  = (q & 3) * 128;
    short* outb = z ? p1 : p0;
    gemm_deep<EPI_BF, 128, 128, 4>(At, 8192, zT, 8192, 512, 4096,
                                   bm, bn, z * 4096, outb, nullptr, nullptr);
}

// out = relu(p0 + p1 + bg). 8 elems/thread, 2048 blocks.
__global__ __launch_bounds__(256)
void k_fin(const short* __restrict__ p0, const short* __restrict__ p1,
           const float* __restrict__ bg, float* __restrict__ out)
{
    const int idx = (blockIdx.x * 256 + threadIdx.x) * 8;
    const int col = idx & 511;
    const bf16x8 a = *(const bf16x8*)&p0[idx];
    const bf16x8 b = *(const bf16x8*)&p1[idx];
    const f32x4 g0 = *(const f32x4*)&bg[col];
    const f32x4 g1 = *(const f32x4*)&bg[col + 4];
    f32x4 o0, o1;
#pragma unroll
    for (int e = 0; e < 4; ++e) {
        o0[e] = fmaxf(b2f(a[e]) + b2f(b[e]) + g0[e], 0.f);
        o1[e] = fmaxf(b2f(a[e + 4]) + b2f(b[e + 4]) + g1[e], 0.f);
    }
    *(f32x4*)&out[idx]     = o0;
    *(f32x4*)&out[idx + 4] = o1;
}

// =========================== helpers =======================================
__global__ __launch_bounds__(256)
void k_cvt(const float* __restrict__ in, short* __restrict__ out)
{
    const int i = (blockIdx.x * 256 + threadIdx.x) * 4;
    const float4 v = *(const float4*)&in[i];
    bf16x4 b;
    b[0] = f2b(v.x); b[1] = f2b(v.y); b[2] = f2b(v.z); b[3] = f2b(v.w);
    *(bf16x4*)&out[i] = b;
}

__global__ __launch_bounds__(256)
void transpose_f32_bf16(const float* __restrict__ in, short* __restrict__ out, int R, int C)
{
    __shared__ short t[32][33];
    const int tx = threadIdx.x, ty = threadIdx.y;
    const int bx = blockIdx.x * 32, by = blockIdx.y * 32;
#pragma unroll
    for (int i = 0; i < 32; i += 8)
        t[ty + i][tx] = f2b(in[(size_t)(by + ty + i) * C + bx + tx]);
    __syncthreads();
#pragma unroll
    for (int i = 0; i < 32; i += 8)
        out[(size_t)(bx + ty + i) * R + by + tx] = t[tx][ty + i];
}

extern "C" void kernel_launch(void* const* d_in, const int* in_sizes, int n_in,
                              void* d_out, int out_size, void* d_ws, size_t ws_size,
                              hipStream_t stream)
{
    const float* x  = (const float*)d_in[0];
    const float* y  = (const float*)d_in[1];
    const float* Wx = (const float*)d_in[2];
    const float* bx = (const float*)d_in[3];
    const float* Wy = (const float*)d_in[4];
    const float* by = (const float*)d_in[5];
    const float* Wg = (const float*)d_in[6];
    const float* bg = (const float*)d_in[7];
    float* out = (float*)d_out;                // [8192, 512] f32

    char* p = (char*)d_ws;
    short* At   = (short*)p;                   // [0, 128 MB)
    short* xb   = (short*)p;                   // 16 MB, aliases At (dead by k_aff)
    short* yb   = (short*)(p + (size_t)8192 * 1024 * 2);   // next 16 MB, ditto
    p += (size_t)8192 * 8192 * 2;
    short* xpb  = (short*)p; p += (size_t)8192 * 512 * 2;
    short* ypb  = (short*)p; p += (size_t)8192 * 512 * 2;
    short* zT   = (short*)p; p += (size_t)512 * 8192 * 2;
    short* WxT  = (short*)p; p += (size_t)512 * 1024 * 2;
    short* WyT  = (short*)p; p += (size_t)512 * 1024 * 2;
    short* WgT  = (short*)p; p += (size_t)512 * 512 * 2;
    float* Dx   = (float*)p; p += (size_t)8192 * 4;
    float* Dy   = (float*)p; p += (size_t)8192 * 4;
    // split-K partials alias xpb/ypb (dead after k_aff)
    short* p0 = xpb;
    short* p1 = ypb;

    hipMemsetAsync(Dx, 0, 2 * 8192 * sizeof(float), stream);  // Dx,Dy contiguous

    dim3 tb(32, 8);
    transpose_f32_bf16<<<dim3(512 / 32, 1024 / 32), tb, 0, stream>>>(Wx, WxT, 1024, 512);
    transpose_f32_bf16<<<dim3(512 / 32, 1024 / 32), tb, 0, stream>>>(Wy, WyT, 1024, 512);
    transpose_f32_bf16<<<dim3(512 / 32, 512 / 32),  tb, 0, stream>>>(Wg, WgT, 512, 512);

    k_cvt<<<8192, 256, 0, stream>>>(x, xb);
    k_cvt<<<8192, 256, 0, stream>>>(y, yb);

    k_proj<<<dim3(4, 128), 256, 0, stream>>>(xb, WxT, bx, xpb, Dx);
    k_proj<<<dim3(4, 128), 256, 0, stream>>>(yb, WyT, by, ypb, Dy);

    k_zT<<<dim3(64, 8), 256, 0, stream>>>(WgT, xpb, zT);

    k_aff<<<2048, 256, 0, stream>>>(ypb, xpb, At, Dy, Dx);

    k_agg<<<512, 256, 0, stream>>>(At, zT, p0, p1);

    k_fin<<<2048, 256, 0, stream>>>(p0, p1, bg, out);
}

// Round 5
// 333.251 us; speedup vs baseline: 1.2838x; 1.0601x over previous
//
#include <hip/hip_runtime.h>
#include <hip/hip_bf16.h>

// BaseQVLayer, R17:
//   xb/yb = bf16(x/y)             (k_cvt, x+y merged)
//   xp = x@Wx+bx; yp = y@Wy+by    (k_proj + row-norms, deep core)
//   zT = Wg^T @ xp^T [512 x 8192] (k_zT, deep core)
//   At[j,i] = 2*(yp_j.xp_i)/(Dx_i+Dy_j)   (k_aff, deep core)
//   p0/p1 = At @ z split-K halves (k_agg, deep core)
//   out = relu(p0+p1+bg)                  (k_fin)
//
// R17 delta: FRAGMENT PREFETCH. R16 post-mortem: SQ_LDS_BANK_CONFLICT is
// exactly 8 x (cp16 instruction count) -- it is the structural 8-pass
// commit of 64-lane x 16B global_load_lds WRITES (async, off critical
// path), NOT read conflicts; reads were already conflict-free. At 256B/cyc
// LDS read BW the LDS unit is ~35% busy -> not the wall. The wall is the
// per-iter latency chain: ds_reads issued and immediately consumed by
// MFMA every iteration -> ~150-250cyc LDS latency exposed per iter
// (MfmaUtil 28%). Fix: per-iter schedule becomes
//   [barrier][stage(t+R-1)][MFMA burst, frags(t) already in regs]
//   [counted waitvm: tile t+1 landed][ds_read frags(t+1)]
// MFMA burst is pure-register; frag-read latency hides under next
// barrier + cp16 issue + compiler's lgkmcnt. Zero extra VGPR (same frag
// arrays, issue point moved). Slot hazards: slot (t-1)%R overwritten at
// iter t was last read end-of-iter t-2, retired before MFMA(t-1),
// double-barrier separated. k_aff RING=3 (L2-hot streams, 1-iter cp16
// age ok); k_agg RING=4 (At from HBM, 2-iter age). k_proj/k_zT ported to
// the same core (old drain core deleted); cvt x/y and Wx/Wy transpose
// launches merged (-2 launch gaps).
//
// Workspace 154.6 MB (unchanged): At [0,128 MB) with xb@0 / yb@16MB
// aliased; xpb 8 | ypb 8 | zT 8 | WxT 1 | WyT 1 | WgT .5 | Dx,Dy.
// p0/p1 alias xpb/ypb (dead after k_aff).

typedef __attribute__((ext_vector_type(8))) short bf16x8;
typedef __attribute__((ext_vector_type(4))) short bf16x4;
typedef __attribute__((ext_vector_type(4))) float f32x4;

__device__ __forceinline__ short f2b(float f) {
    unsigned int u = __builtin_bit_cast(unsigned int, f);
    unsigned int r = (u + 0x7fffu + ((u >> 16) & 1u)) >> 16;
    return (short)r;
}
__device__ __forceinline__ float b2f(short s) {
    unsigned int u = ((unsigned int)(unsigned short)s) << 16;
    return __builtin_bit_cast(float, u);
}

// async global->LDS, 16 B/lane. LDS dest = wave-uniform base + lane*16.
__device__ __forceinline__ void cp16(const void* g, void* l) {
    __builtin_amdgcn_global_load_lds(
        (const __attribute__((address_space(1))) void*)g,
        (__attribute__((address_space(3))) void*)l, 16, 0, 0);
}

template<int N>
__device__ __forceinline__ void waitvm() {
    if constexpr (N == 0)      asm volatile("s_waitcnt vmcnt(0)" ::: "memory");
    else if constexpr (N == 3) asm volatile("s_waitcnt vmcnt(3)" ::: "memory");
    else if constexpr (N == 4) asm volatile("s_waitcnt vmcnt(4)" ::: "memory");
    else if constexpr (N == 6) asm volatile("s_waitcnt vmcnt(6)" ::: "memory");
    else if constexpr (N == 8) asm volatile("s_waitcnt vmcnt(8)" ::: "memory");
    else static_assert(N == 0, "unsupported vmcnt literal");
}

// granule slot permutation (kept from R16; harmless, read-conflict-free)
__device__ __forceinline__ int gslot(int c, int row) {
    return c ^ (row & 3) ^ ((row >> 2) & 3);
}

constexpr int EPI_XP = 0;  // +bias, store bf16, atomic row-norm
constexpr int EPI_BF = 1;  // store bf16 (zT, k_agg partials)
constexpr int EPI_AT = 2;  // dice scale (rcp), store bf16

// ===================== deep-pipelined core (all GEMMs) =====================
// 256 threads, waves 2x2: wave tile (TM/2) x (TN/2). BK=32, RING LDS slots,
// raw s_barrier + counted vmcnt, cp16 staged RING-1 tiles ahead, fragments
// prefetched ONE tile ahead in registers (MFMA burst is pure-register).
template<int EPI, int TM, int TN, int RING>
__device__ __forceinline__ void gemm_deep(
    const short* __restrict__ A, int lda,
    const short* __restrict__ Bt, int ldb,
    int N, int K, int bm, int bn, int kbase,
    const float* __restrict__ bias,
    short* __restrict__ outb,
    float* __restrict__ Dacc,
    const float* __restrict__ Drow, const float* __restrict__ Dcol)
{
    constexpr int FRM = TM / 32;           // frags per wave along m
    constexpr int FRN = TN / 32;           // frags per wave along n
    constexpr int CPA = TM * 4 / 256;      // cp16/thread for A tile
    constexpr int CPB = TN * 4 / 256;      // cp16/thread for B tile
    constexpr int CPT = CPA + CPB;
    __shared__ __align__(16) short As[RING][TM * 32];
    __shared__ __align__(16) short Bs[RING][TN * 32];

    const int tid  = threadIdx.x;
    const int wave = tid >> 6;
    const int lane = tid & 63;
    const int quad = lane >> 4;
    const int l15  = lane & 15;
    const int wm   = (wave >> 1) * (FRM * 16);
    const int wn   = (wave & 1) * (FRN * 16);
    const int nk   = K / 32;

    f32x4 acc[FRM][FRN];
#pragma unroll
    for (int i = 0; i < FRM; i++)
#pragma unroll
        for (int j = 0; j < FRN; j++) acc[i][j] = f32x4{0.f, 0.f, 0.f, 0.f};

    auto stage = [&](int slot, int t) {
        const int k0 = kbase + t * 32;
#pragma unroll
        for (int s = 0; s < CPA; s++) {
            const int seg = tid + 256 * s;
            const int row = seg >> 2, c8 = seg & 3;
            const int gg  = gslot(c8, row);
            cp16(&A[(size_t)(bm + row) * lda + k0 + gg * 8], &As[slot][seg * 8]);
        }
#pragma unroll
        for (int s = 0; s < CPB; s++) {
            const int seg = tid + 256 * s;
            const int row = seg >> 2, c8 = seg & 3;
            const int gg  = gslot(c8, row);
            cp16(&Bt[(size_t)(bn + row) * ldb + k0 + gg * 8], &Bs[slot][seg * 8]);
        }
    };

    bf16x8 a[FRM], b[FRN];
    auto ldfrag = [&](int slot) {
#pragma unroll
        for (int i = 0; i < FRM; i++) {
            const int row = wm + i * 16 + l15;
            a[i] = *(const bf16x8*)&As[slot][row * 32 + (gslot(quad, row) << 3)];
        }
#pragma unroll
        for (int j = 0; j < FRN; j++) {
            const int row = wn + j * 16 + l15;
            b[j] = *(const bf16x8*)&Bs[slot][row * 32 + (gslot(quad, row) << 3)];
        }
    };

#pragma unroll
    for (int p = 0; p < RING - 1; ++p) stage(p, p);   // cp16 prefill
    waitvm<(RING - 2) * CPT>();                        // tile 0 landed
    ldfrag(0);                                         // frags(0) in regs

    int cur = 0, prv = RING - 1;
    for (int t = 0; t < nk; ++t) {
        __builtin_amdgcn_s_barrier();
        // slot prv == (t-1)%RING: last frag-read at end of iter t-2,
        // retired before MFMA(t-1); two barriers separate it from this write.
        if (t + RING - 1 < nk) stage(prv, t + RING - 1);

        __builtin_amdgcn_s_setprio(1);
#pragma unroll
        for (int i = 0; i < FRM; i++)
#pragma unroll
            for (int j = 0; j < FRN; j++)
                acc[i][j] = __builtin_amdgcn_mfma_f32_16x16x32_bf16(a[i], b[j], acc[i][j], 0, 0, 0);
        __builtin_amdgcn_s_setprio(0);
        __builtin_amdgcn_sched_barrier(0);

        if (t + 1 < nk) {
            // tile t+1 landed when only stages for tiles > t+1 remain
            if constexpr (RING == 3) {
                if (t + 2 < nk) waitvm<CPT>(); else waitvm<0>();
            } else {
                if (t + 3 < nk)      waitvm<2 * CPT>();
                else if (t + 2 < nk) waitvm<CPT>();
                else                 waitvm<0>();
            }
            ldfrag((cur + 1 == RING) ? 0 : cur + 1);   // frags(t+1)
        }
        prv = cur;
        cur = (cur + 1 == RING) ? 0 : cur + 1;
    }

    // C/D layout: col = lane&15, row = quad*4 + r  [m89/m91]
#pragma unroll
    for (int im = 0; im < FRM; ++im) {
#pragma unroll
        for (int r = 0; r < 4; ++r) {
            const int gm = bm + wm + im * 16 + quad * 4 + r;
            if (EPI == EPI_XP) {
                float s = 0.f;
#pragma unroll
                for (int jn = 0; jn < FRN; ++jn) {
                    const int gn = bn + wn + jn * 16 + l15;
                    const float v = acc[im][jn][r] + bias[gn];
                    outb[(size_t)gm * N + gn] = f2b(v);
                    s += v * v;
                }
#pragma unroll
                for (int m = 1; m < 16; m <<= 1) s += __shfl_xor(s, m, 64);
                if (l15 == 0) atomicAdd(&Dacc[gm], s);
            } else if (EPI == EPI_AT) {
                const float dy = Drow[gm];
#pragma unroll
                for (int jn = 0; jn < FRN; ++jn) {
                    const int gn = bn + wn + jn * 16 + l15;
                    const float v = 2.f * acc[im][jn][r] * __builtin_amdgcn_rcpf(Dcol[gn] + dy);
                    outb[(size_t)gm * N + gn] = f2b(v);
                }
            } else {  // EPI_BF
#pragma unroll
                for (int jn = 0; jn < FRN; ++jn) {
                    const int gn = bn + wn + jn * 16 + l15;
                    outb[(size_t)gm * N + gn] = f2b(acc[im][jn][r]);
                }
            }
        }
    }
}

// xp/yp = x@W + b, row norms. grid(4,128), tile 64x128, RING=4 (48 KB LDS).
__global__ __launch_bounds__(256)
void k_proj(const short* __restrict__ A, const short* __restrict__ Bt,
            const float* __restrict__ bias, short* __restrict__ outb,
            float* __restrict__ Dacc)
{
    gemm_deep<EPI_XP, 64, 128, 4>(A, 1024, Bt, 1024, 512, 1024,
                                  blockIdx.y * 64, blockIdx.x * 128, 0,
                                  bias, outb, Dacc, nullptr, nullptr);
}

// zT = Wg^T @ xp^T  [512 x 8192] bf16. grid(64,8), tile 64x128, K=512.
__global__ __launch_bounds__(256)
void k_zT(const short* __restrict__ WgT, const short* __restrict__ xpb,
          short* __restrict__ zT)
{
    gemm_deep<EPI_BF, 64, 128, 4>(WgT, 512, xpb, 512, 8192, 512,
                                  blockIdx.y * 64, blockIdx.x * 128, 0,
                                  nullptr, zT, nullptr, nullptr, nullptr);
}

// At[j,i]. flat grid 2048; tile 256x128 (wave 128x64), RING=3 (72 KB LDS,
// 2 blk/CU). XCD x owns j-band; 4 consecutive blocks share an xp 128-row
// tile (L2). Both streams L2-hot -> 1-iter cp16 age suffices.
__global__ __launch_bounds__(256, 2)
void k_aff(const short* __restrict__ ypb, const short* __restrict__ xpb,
           short* __restrict__ At, const float* __restrict__ Dy,
           const float* __restrict__ Dx)
{
    const int flat = blockIdx.x;
    const int xcd = flat & 7;
    const int q   = flat >> 3;            // 0..255
    const int by  = xcd * 4 + (q & 3);    // 0..31  (j tiles of 256)
    const int bx  = q >> 2;               // 0..63  (i tiles of 128)
    gemm_deep<EPI_AT, 256, 128, 3>(ypb, 512, xpb, 512, 8192, 512,
                                   by * 256, bx * 128, 0,
                                   nullptr, At, nullptr, Dy, Dx);
}

// Split-K At@z partials. tile 128x128, RING=4 (64 KB LDS, 2 blk/CU; At from
// HBM -> 2-iter cp16 age), grid 512. Group = (bm,z): its 4 bn-blocks on one
// XCD so the 1 MB At slice is L2-shared; z-halves read disjoint At columns.
__global__ __launch_bounds__(256, 2)
void k_agg(const short* __restrict__ At, const short* __restrict__ zT,
           short* __restrict__ p0, short* __restrict__ p1)
{
    const int flat = blockIdx.x;
    const int xcd = flat & 7;
    const int q   = flat >> 3;            // 0..63 within XCD
    const int g   = xcd * 16 + (q >> 2);  // group 0..127 = (bm, z)
    const int bm  = (g >> 1) * 128;
    const int z   = g & 1;
    const int bn  = (q & 3) * 128;
    short* outb = z ? p1 : p0;
    gemm_deep<EPI_BF, 128, 128, 4>(At, 8192, zT, 8192, 512, 4096,
                                   bm, bn, z * 4096,
                                   nullptr, outb, nullptr, nullptr, nullptr);
}

// out = relu(p0 + p1 + bg). 8 elems/thread, 2048 blocks.
__global__ __launch_bounds__(256)
void k_fin(const short* __restrict__ p0, const short* __restrict__ p1,
           const float* __restrict__ bg, float* __restrict__ out)
{
    const int idx = (blockIdx.x * 256 + threadIdx.x) * 8;
    const int col = idx & 511;
    const bf16x8 a = *(const bf16x8*)&p0[idx];
    const bf16x8 b = *(const bf16x8*)&p1[idx];
    const f32x4 g0 = *(const f32x4*)&bg[col];
    const f32x4 g1 = *(const f32x4*)&bg[col + 4];
    f32x4 o0, o1;
#pragma unroll
    for (int e = 0; e < 4; ++e) {
        o0[e] = fmaxf(b2f(a[e]) + b2f(b[e]) + g0[e], 0.f);
        o1[e] = fmaxf(b2f(a[e + 4]) + b2f(b[e + 4]) + g1[e], 0.f);
    }
    *(f32x4*)&out[idx]     = o0;
    *(f32x4*)&out[idx + 4] = o1;
}

// =========================== helpers =======================================
// x and y cvt merged: grid(8192, 2), blockIdx.y selects stream.
__global__ __launch_bounds__(256)
void k_cvt(const float* __restrict__ x, const float* __restrict__ y,
           short* __restrict__ xb, short* __restrict__ yb)
{
    const float* in  = blockIdx.y ? y  : x;
    short*       out = blockIdx.y ? yb : xb;
    const int i = (blockIdx.x * 256 + threadIdx.x) * 4;
    const float4 v = *(const float4*)&in[i];
    bf16x4 b;
    b[0] = f2b(v.x); b[1] = f2b(v.y); b[2] = f2b(v.z); b[3] = f2b(v.w);
    *(bf16x4*)&out[i] = b;
}

__device__ __forceinline__ void transpose_body(
    const float* __restrict__ in, short* __restrict__ out, int R, int C)
{
    __shared__ short t[32][33];
    const int tx = threadIdx.x, ty = threadIdx.y;
    const int bx = blockIdx.x * 32, by = blockIdx.y * 32;
#pragma unroll
    for (int i = 0; i < 32; i += 8)
        t[ty + i][tx] = f2b(in[(size_t)(by + ty + i) * C + bx + tx]);
    __syncthreads();
#pragma unroll
    for (int i = 0; i < 32; i += 8)
        out[(size_t)(bx + ty + i) * R + by + tx] = t[tx][ty + i];
}

// Wx and Wy transposed in one launch: grid(16, 32, 2), z selects matrix.
__global__ __launch_bounds__(256)
void t_wxy(const float* __restrict__ Wx, const float* __restrict__ Wy,
           short* __restrict__ WxT, short* __restrict__ WyT)
{
    transpose_body(blockIdx.z ? Wy : Wx, blockIdx.z ? WyT : WxT, 1024, 512);
}

__global__ __launch_bounds__(256)
void t_wg(const float* __restrict__ Wg, short* __restrict__ WgT)
{
    transpose_body(Wg, WgT, 512, 512);
}

extern "C" void kernel_launch(void* const* d_in, const int* in_sizes, int n_in,
                              void* d_out, int out_size, void* d_ws, size_t ws_size,
                              hipStream_t stream)
{
    const float* x  = (const float*)d_in[0];
    const float* y  = (const float*)d_in[1];
    const float* Wx = (const float*)d_in[2];
    const float* bx = (const float*)d_in[3];
    const float* Wy = (const float*)d_in[4];
    const float* by = (const float*)d_in[5];
    const float* Wg = (const float*)d_in[6];
    const float* bg = (const float*)d_in[7];
    float* out = (float*)d_out;                // [8192, 512] f32

    char* p = (char*)d_ws;
    short* At   = (short*)p;                   // [0, 128 MB)
    short* xb   = (short*)p;                   // 16 MB, aliases At (dead by k_aff)
    short* yb   = (short*)(p + (size_t)8192 * 1024 * 2);   // next 16 MB, ditto
    p += (size_t)8192 * 8192 * 2;
    short* xpb  = (short*)p; p += (size_t)8192 * 512 * 2;
    short* ypb  = (short*)p; p += (size_t)8192 * 512 * 2;
    short* zT   = (short*)p; p += (size_t)512 * 8192 * 2;
    short* WxT  = (short*)p; p += (size_t)512 * 1024 * 2;
    short* WyT  = (short*)p; p += (size_t)512 * 1024 * 2;
    short* WgT  = (short*)p; p += (size_t)512 * 512 * 2;
    float* Dx   = (float*)p; p += (size_t)8192 * 4;
    float* Dy   = (float*)p; p += (size_t)8192 * 4;
    // split-K partials alias xpb/ypb (dead after k_aff)
    short* p0 = xpb;
    short* p1 = ypb;

    hipMemsetAsync(Dx, 0, 2 * 8192 * sizeof(float), stream);  // Dx,Dy contiguous

    dim3 tb(32, 8);
    t_wxy<<<dim3(16, 32, 2), tb, 0, stream>>>(Wx, Wy, WxT, WyT);
    t_wg<<<dim3(16, 16), tb, 0, stream>>>(Wg, WgT);

    k_cvt<<<dim3(8192, 2), 256, 0, stream>>>(x, y, xb, yb);

    k_proj<<<dim3(4, 128), 256, 0, stream>>>(xb, WxT, bx, xpb, Dx);
    k_proj<<<dim3(4, 128), 256, 0, stream>>>(yb, WyT, by, ypb, Dy);

    k_zT<<<dim3(64, 8), 256, 0, stream>>>(WgT, xpb, zT);

    k_aff<<<2048, 256, 0, stream>>>(ypb, xpb, At, Dy, Dx);

    k_agg<<<512, 256, 0, stream>>>(At, zT, p0, p1);

    k_fin<<<2048, 256, 0, stream>>>(p0, p1, bg, out);
}